// Round 9
// baseline (278.698 us; speedup 1.0000x reference)
//
#include <hip/hip_runtime.h>
#include <hip/hip_bf16.h>

typedef __attribute__((ext_vector_type(8)))  short bf16x8;   // 8 bf16 = 4 VGPRs
typedef __attribute__((ext_vector_type(16))) float f32x16;   // 32x32 MFMA accumulator

constexpr int Bn = 32, Cn = 64, Hn = 64, Wn = 256, On = 64, En = 4, Rn = 4;
constexpr float SCALE = 1.0f / Rn;

// packed-x geometry (round-1/7-verified layout): per (b,h) row, 258 slots x 128B,
// slot s holds c=0..63 of x[b][:][h][s-1], c-group cb at byte ((cb^(s&7))*16),
// slots 0 and 257 are zero (SAME-padding halo).
constexpr int ROW_B  = 258 * 128;   // 33024 B per packed row

constexpr int WTILE  = 64;          // w per conv block
constexpr int HSTRIP = 16;          // output rows per conv block (2 rows/iter)
constexpr int SLOT_B = 66 * 128;    // 8448 B conv ring slot (slots w0..w0+65)

constexpr size_t WFRAG_B = 294912;
constexpr size_t XP_B    = (size_t)Bn * Hn * ROW_B;   // 67,633,152
constexpr size_t ZROW_B  = ROW_B;                     // zero row for h-OOB

#define GLOAD_LDS16(SRC, DST) \
    __builtin_amdgcn_global_load_lds( \
        (const __attribute__((address_space(1))) void*)(SRC), \
        (__attribute__((address_space(3))) void*)(DST), 16, 0, 0)

// ---------------------------------------------------------------------------
// Merge LoRA into conv weights, in 32x32x16 A-fragment order (unchanged):
// Wfrag[e][mh][s][lane][j]:  o = mh*32 + (lane&31),
//   k: tap = s>>2, c = (s&3)*16 + (lane>>5)*8 + j
// ---------------------------------------------------------------------------
__global__ __launch_bounds__(256) void merge_k(
    const float* __restrict__ Wc, const float* __restrict__ Wa,
    const float* __restrict__ Wb, __hip_bfloat16* __restrict__ Wfrag)
{
    int t = blockIdx.x * 256 + threadIdx.x;          // 0..147455 exact
    int j    = t & 7;
    int lane = (t >> 3) & 63;
    int g    = t >> 9;                               // (e*2+mh)*36 + s
    int s    = g % 36;
    int mh   = (g / 36) & 1;
    int e    = g / 72;
    int m = lane & 31, half = lane >> 5;
    int o = mh * 32 + m;
    int tap = s >> 2, cq = s & 3;
    int c = cq * 16 + half * 8 + j;
    float acc = Wc[(o * Cn + c) * 9 + tap];
#pragma unroll
    for (int r = 0; r < Rn; ++r)
        acc += SCALE * Wb[(e * On + o) * Rn + r] * Wa[((e * Rn + r) * Cn + c) * 9 + tap];
    Wfrag[t] = __float2bfloat16(acc);
}

// ---------------------------------------------------------------------------
// Pack pass v2 (round-8-verified): x fp32 NCHW -> xp bf16 ring-image rows.
// Full 128B-line loads and stores. Tail blocks zero halo slots + zero-row.
// ---------------------------------------------------------------------------
__global__ __launch_bounds__(256) void pack2_k(
    const float* __restrict__ x, __hip_bfloat16* __restrict__ xp,
    __hip_bfloat16* __restrict__ zr)
{
    const int blk = blockIdx.x;
    if (blk < 4096) {
        int l  = ((blk & 1) << 8) | threadIdx.x;     // 0..511 within row team
        int bh = blk >> 1;                           // b*64 + h
        int wLo = l & 3, cb = (l >> 2) & 7, wHi = l >> 5;
        int wq = wHi * 4 + wLo;                      // 0..63
        int b = bh >> 6, h = bh & 63;
        const float* src = x + (((size_t)(b * Cn + cb * 8) * Hn + h) * Wn) + 4 * wq;
        float4 f[8];
#pragma unroll
        for (int i = 0; i < 8; ++i)
            f[i] = *reinterpret_cast<const float4*>(src + (size_t)i * Hn * Wn);
        char* row = (char*)xp + (size_t)bh * ROW_B;
#pragma unroll
        for (int j = 0; j < 4; ++j) {
            union { __hip_bfloat16 u[8]; bf16x8 v; } pk;
#pragma unroll
            for (int i = 0; i < 8; ++i) {
                float v = (j == 0) ? f[i].x : (j == 1) ? f[i].y : (j == 2) ? f[i].z : f[i].w;
                pk.u[i] = __float2bfloat16(v);
            }
            int s = 4 * wq + 1 + j;                  // 1..256
            *reinterpret_cast<bf16x8*>(row + s * 128 + ((cb ^ (s & 7)) * 16)) = pk.v;
        }
    } else if (blk < 4096 + 128) {
        int z = (blk - 4096) * 256 + threadIdx.x;    // 0..32767
        int cb = z & 7, t = (z >> 3) & 1, bh = z >> 4;
        char* row = (char*)xp + (size_t)bh * ROW_B;
        bf16x8 zz = {};
        *reinterpret_cast<bf16x8*>(row + (t ? 257 : 0) * 128 + cb * 16) = zz;
    } else {
        int t = (blk - 4096 - 128) * 256 + threadIdx.x;
        if (t < ROW_B / 16) {
            bf16x8 zz = {};
            reinterpret_cast<bf16x8*>(zr)[t] = zz;
        }
    }
}

// ---------------------------------------------------------------------------
// Fused conv, v11 = v10 + two-output-rows-per-iteration with fragment reuse.
// Output rows (st, st+1) share x-rows st..st+1: each shared fragment read
// feeds TWO MFMAs (different wf[s], same B operand) -> 48 ds_read_b128 per
// 72 MFMAs (was 72), one barrier + one store burst per 2 rows.
// HSTRIP=16 -> 512 blocks = exactly 2/CU (zero tail), h-halo 18/16 (was 10/8).
// Ring: 8 slots x 8448 B = 67.6 KB (2 blocks = 135 KB <= 160).
// Counted barrier: per iter 6 DMA then 32 stores -> s_waitcnt vmcnt(32)
// retires this iter's DMAs, leaves the 32 newest (stores) in flight.
// Acc: aA/aB (2 rows x 1 chain) = 32 VGPRs, same as v10's a0/a1.
// ---------------------------------------------------------------------------
__global__ __launch_bounds__(256, 2) void conv11_k(
    const __hip_bfloat16* __restrict__ xp, const __hip_bfloat16* __restrict__ zr,
    const int* __restrict__ sid, const __hip_bfloat16* __restrict__ Wfrag,
    float* __restrict__ out)
{
    __shared__ __align__(16) char xs[8 * SLOT_B];        // 67584 B ring

    // XCD-chunked bijective swizzle (512 blocks, 512%8==0): the 16 tiles of a
    // batch stay on one XCD -> by-neighbor halo rows L2-hit.
    const int logical = ((blockIdx.x & 7) << 6) | (blockIdx.x >> 3);
    const int tile = logical & 15;
    const int bx = tile & 3, by = tile >> 2, b = logical >> 4;

    const int tid = threadIdx.x;
    const int w0  = bx * WTILE;
    const int h0  = by * HSTRIP;
    const int e   = sid[b];
    const size_t HW = (size_t)Hn * Wn;

    const int lane = tid & 63, wave = tid >> 6;
    const int mh = wave & 1, nh = wave >> 1;
    const int n = lane & 31, half = lane >> 5;

    // A fragments: 36 x bf16x8, loaded once (L2-resident), live in VGPRs/AGPRs.
    bf16x8 wf[36];
    const bf16x8* wg = reinterpret_cast<const bf16x8*>(Wfrag) + (size_t)(e * 2 + mh) * 36 * 64;
#pragma unroll
    for (int s = 0; s < 36; ++s) wf[s] = wg[s * 64 + lane];

    // window of packed row (b,gh) for this w-tile: slots w0..w0+65, contiguous
    const char* xpb = (const char*)xp + (size_t)b * Hn * ROW_B + (size_t)w0 * 128;
    const char* zrw = (const char*)zr + (size_t)w0 * 128;
    const int lofs = wave * 1024 + lane * 16;            // per-lane source offset

    auto stage = [&](int rx) {
        const int gh = h0 + rx;
        const char* src = ((unsigned)gh < (unsigned)Hn) ? (xpb + (size_t)gh * ROW_B) : zrw;
        char* dst = xs + ((rx + 1) & 7) * SLOT_B + wave * 1024;   // wave-uniform dest
        GLOAD_LDS16(src + lofs,        dst);
        GLOAD_LDS16(src + 4096 + lofs, dst + 4096);
        GLOAD_LDS16(src + 4352 + lofs, dst + 4352);   // tail via benign overlap
    };

    // prologue: x rows h0-1 .. h0+2 -> slots 0..3 (full drain once)
    stage(-1); stage(0); stage(1); stage(2);
    asm volatile("s_waitcnt vmcnt(0) lgkmcnt(0)" ::: "memory");
    __builtin_amdgcn_s_barrier();

    for (int st = 0; st < HSTRIP; st += 2) {
        // 1. DMA rows st+3, st+4 (consumed next iteration; slots free: their
        //    previous tenants' last readers were >=2 barriers ago)
        if (st + 4 <= HSTRIP) { stage(st + 3); stage(st + 4); }
        asm volatile("" ::: "memory");   // pin DMA issue before epilogue stores

        // 2. compute output rows (h0+st, h0+st+1); x-rows st-1+k, k=0..3.
        //    Row A (st): dh=k (k=0..2);  Row B (st+1): dh=k-1 (k=1..3).
        f32x16 aA, aB;
#pragma unroll
        for (int i = 0; i < 16; ++i) { aA[i] = 0.0f; aB[i] = 0.0f; }

#pragma unroll
        for (int k = 0; k < 4; ++k) {
            const int slotbase = ((st + k) & 7) * SLOT_B;   // row st-1+k
#pragma unroll
            for (int dw = 0; dw < 3; ++dw) {
                const int ww = nh * 32 + n + dw;             // 0..65
                const char* pbase = xs + slotbase + ww * 128;
#pragma unroll
                for (int cq = 0; cq < 4; ++cq) {
                    bf16x8 bf = *reinterpret_cast<const bf16x8*>(
                        pbase + (((cq * 2 + half) ^ (ww & 7)) * 16));
                    if (k <= 2) {
                        const int s = (k * 3 + dw) * 4 + cq;
                        aA = __builtin_amdgcn_mfma_f32_32x32x16_bf16(wf[s], bf, aA, 0, 0, 0);
                    }
                    if (k >= 1) {
                        const int s = ((k - 1) * 3 + dw) * 4 + cq;
                        aB = __builtin_amdgcn_mfma_f32_32x32x16_bf16(wf[s], bf, aB, 0, 0, 0);
                    }
                }
            }
        }

        // 3. epilogue: direct global stores, 2 rows; lanes n=0..31 cover 128B
        //    contiguous at (o = mh*32 + 4*half + (r&3)+8*(r>>2), rows st,st+1).
        {
            size_t base = ((size_t)(b * On + mh * 32 + 4 * half) * Hn + (h0 + st)) * Wn
                          + w0 + nh * 32 + n;
#pragma unroll
            for (int r = 0; r < 16; ++r) {
                int o_off = (r & 3) + 8 * (r >> 2);
                out[base + (size_t)o_off * HW]      = aA[r];
                out[base + (size_t)o_off * HW + Wn] = aB[r];
            }
        }

        // 4. counted-vmcnt barrier: retire this iter's 6 DMAs, keep the 32
        //    newest (this iter's stores) in flight across the barrier.
        asm volatile("s_waitcnt vmcnt(32) lgkmcnt(0)" ::: "memory");
        __builtin_amdgcn_s_barrier();
    }
}

// ---------------------------------------------------------------------------
// Fallback (ws too small): round-6 kernel verbatim (reg-staged, 101us).
// ---------------------------------------------------------------------------
constexpr int FB_WTILE  = 32;
constexpr int FB_HSTRIP = 16;
constexpr int FB_SLOT_B = 34 * 128;

__device__ __forceinline__ int fb_swz(int ww, int cb) {
    return ww * 128 + ((cb ^ ((ww >> 2) & 7)) * 16);
}

__global__ __launch_bounds__(128, 2) void conv8_k(
    const float* __restrict__ x, const int* __restrict__ sid,
    const __hip_bfloat16* __restrict__ Wfrag, float* __restrict__ out)
{
    __shared__ __align__(16) char xs[4 * FB_SLOT_B];

    const int tid = threadIdx.x;
    const int w0  = blockIdx.x * FB_WTILE;
    const int h0  = blockIdx.y * FB_HSTRIP;
    const int b   = blockIdx.z;
    const int e   = sid[b];
    const size_t HW = (size_t)Hn * Wn;

    const int lane = tid & 63, mh = tid >> 6;
    const int n = lane & 31, half = lane >> 5;

    bf16x8 wf[36];
    const bf16x8* wg = reinterpret_cast<const bf16x8*>(Wfrag) + (size_t)(e * 2 + mh) * 36 * 64;
#pragma unroll
    for (int s = 0; s < 36; ++s) wf[s] = wg[s * 64 + lane];

    const int pb = tid >> 3, q = tid & 7;
    const float* xbase = x + ((size_t)b * Cn + pb * 4) * HW + w0 + 4 * q;

    const int hside = tid >> 6, hc = tid & 63;
    const int gwh   = hside ? (w0 + FB_WTILE) : (w0 - 1);
    const bool hv   = (unsigned)gwh < (unsigned)Wn;
    const float* hbase = x + ((size_t)b * Cn + hc) * HW + gwh;

    auto stage_load = [&](float4 (&f)[4], float& hx, int rx) {
        const int gh = h0 + rx;
        if ((unsigned)gh < (unsigned)Hn) {
            const float* src = xbase + (size_t)gh * Wn;
#pragma unroll
            for (int r = 0; r < 4; ++r)
                f[r] = *reinterpret_cast<const float4*>(src + r * HW);
            hx = hv ? hbase[(size_t)gh * Wn] : 0.0f;
        } else {
            float4 z4 = make_float4(0.0f, 0.0f, 0.0f, 0.0f);
#pragma unroll
            for (int r = 0; r < 4; ++r) f[r] = z4;
            hx = 0.0f;
        }
    };
    auto stage_store = [&](float4 (&f)[4], float& hx, int rx) {
        const int slot = (rx + 1) & 3;
        char* dbase = xs + slot * FB_SLOT_B;
        const int cb = pb >> 1, sub = (pb & 1) * 8;
#pragma unroll
        for (int j = 0; j < 4; ++j) {
            union { __hip_bfloat16 u[4]; short4 v; } pk;
#pragma unroll
            for (int r = 0; r < 4; ++r) {
                float v = (j == 0) ? f[r].x : (j == 1) ? f[r].y : (j == 2) ? f[r].z : f[r].w;
                pk.u[r] = __float2bfloat16(v);
            }
            int ww = 4 * q + 1 + j;
            *reinterpret_cast<short4*>(dbase + fb_swz(ww, cb) + sub) = pk.v;
        }
        {
            __hip_bfloat16 hb = __float2bfloat16(hx);
            int ww = hside ? (FB_WTILE + 1) : 0;
            *reinterpret_cast<__hip_bfloat16*>(dbase + fb_swz(ww, hc >> 3) + (hc & 7) * 2) = hb;
        }
    };

    auto barrier = [&]() {
        asm volatile("s_waitcnt lgkmcnt(0)" ::: "memory");
        __builtin_amdgcn_s_barrier();
    };

    float4 fA[4], fB[4];
    float  hxA, hxB;

    stage_load(fA, hxA, -1); stage_store(fA, hxA, -1);
    stage_load(fA, hxA, 0);  stage_store(fA, hxA, 0);
    stage_load(fA, hxA, 1);  stage_store(fA, hxA, 1);
    stage_load(fA, hxA, 2);
    barrier();

    for (int st = 0; st < FB_HSTRIP; ++st) {
        const bool do_issue = (st + 3 <= FB_HSTRIP);
        if (do_issue) {
            if (st & 1) stage_load(fA, hxA, st + 3);
            else        stage_load(fB, hxB, st + 3);
        }

        f32x16 a;
#pragma unroll
        for (int i = 0; i < 16; ++i) a[i] = 0.0f;

#pragma unroll
        for (int s = 0; s < 36; ++s) {
            const int tap = s >> 2, cq = s & 3;
            const int dh = tap / 3, dw = tap % 3;
            const int slotbase = ((st + dh) & 3) * FB_SLOT_B;
            int ww = n + dw;
            bf16x8 bf = *reinterpret_cast<const bf16x8*>(xs + slotbase + fb_swz(ww, cq * 2 + half));
            a = __builtin_amdgcn_mfma_f32_32x32x16_bf16(wf[s], bf, a, 0, 0, 0);
        }

        const bool do_store = (st + 2 <= FB_HSTRIP);
        if (do_store) {
            if (st & 1) stage_store(fB, hxB, st + 2);
            else        stage_store(fA, hxA, st + 2);
        }

        {
            const int hrow = h0 + st;
            size_t base = ((size_t)(b * On + mh * 32 + 4 * half) * Hn + hrow) * Wn + w0 + n;
#pragma unroll
            for (int r = 0; r < 16; ++r) {
                int o_off = (r & 3) + 8 * (r >> 2);
                out[base + (size_t)o_off * HW] = a[r];
            }
        }

        barrier();
    }
}

// ---------------------------------------------------------------------------
extern "C" void kernel_launch(void* const* d_in, const int* in_sizes, int n_in,
                              void* d_out, int out_size, void* d_ws, size_t ws_size,
                              hipStream_t stream)
{
    const float* x   = (const float*)d_in[0];
    const int*   sid = (const int*)d_in[1];
    const float* Wc  = (const float*)d_in[2];
    const float* Wa  = (const float*)d_in[3];
    const float* Wb  = (const float*)d_in[4];
    float*       out = (float*)d_out;

    __hip_bfloat16* Wfrag = (__hip_bfloat16*)d_ws;

    merge_k<<<En * 2 * 36 * 64 * 8 / 256, 256, 0, stream>>>(Wc, Wa, Wb, Wfrag);

    const size_t NEED = WFRAG_B + XP_B + ZROW_B;   // 67,961,088
    if (ws_size >= NEED) {
        __hip_bfloat16* xp = (__hip_bfloat16*)((char*)d_ws + WFRAG_B);
        __hip_bfloat16* zw = (__hip_bfloat16*)((char*)d_ws + WFRAG_B + XP_B);
        pack2_k<<<4096 + 128 + 9, 256, 0, stream>>>(x, xp, zw);
        conv11_k<<<dim3(512, 1, 1), 256, 0, stream>>>(xp, zw, sid, Wfrag, out);
    } else {
        dim3 grid(Wn / FB_WTILE, Hn / FB_HSTRIP, Bn);
        conv8_k<<<grid, 128, 0, stream>>>(x, sid, Wfrag, out);
    }
}